// Round 12
// baseline (365.259 us; speedup 1.0000x reference)
//
#include <hip/hip_runtime.h>
#include <hip/hip_bf16.h>

// Problem constants (AdaptiveMobiusLayer): B=4, S=4096, DIM=1024
#define PB 4
#define PS 4096
#define PD 1024
#define ROWS (PB * PS)          // 16384
#define NUM_CYCLES 3
#define BASE_COUPLING 0.1f

typedef __attribute__((ext_vector_type(8))) short bf16x8;
typedef __attribute__((ext_vector_type(4))) float f32x4;

// ---------------- helpers ----------------
__device__ __forceinline__ float geluf(float x) {
    return 0.5f * x * (1.0f + erff(x * 0.70710678118654752440f));
}
// tanh-form GELU: max abs err ~3e-4 (<< bf16 rounding already present)
__device__ __forceinline__ float gelu_fast(float x) {
    float u = (x + 0.044715f * x * x * x) * 2.3022077f;  // 2*0.7978845608*log2(e)
    return x * __builtin_amdgcn_rcpf(1.0f + exp2f(-u));
}
__device__ __forceinline__ float sigmf_(float x) {
    return 1.0f / (1.0f + expf(-x));
}
__device__ __forceinline__ uint2 pk4(float4 v) {
    __hip_bfloat16 h[4] = {__float2bfloat16(v.x), __float2bfloat16(v.y),
                           __float2bfloat16(v.z), __float2bfloat16(v.w)};
    return *reinterpret_cast<uint2*>(h);
}
__device__ __forceinline__ float4 axpy4(float4 a, float s, float4 b) {
    return make_float4(fmaf(s, b.x, a.x), fmaf(s, b.y, a.y),
                       fmaf(s, b.z, a.z), fmaf(s, b.w, a.w));
}
__device__ __forceinline__ float bf2f(unsigned short u) {
    unsigned int w = ((unsigned int)u) << 16;
    return __builtin_bit_cast(float, w);
}
__device__ __forceinline__ float4 ubf2f4(uint2 u) {
    unsigned short h[4];
    *reinterpret_cast<uint2*>(h) = u;
    return make_float4(bf2f(h[0]), bf2f(h[1]), bf2f(h[2]), bf2f(h[3]));
}

// global_load_lds: 16B per lane, LDS dest = wave-uniform base + lane*16
#define GLD_LDS16(gsrc, ldst)                                                        \
    __builtin_amdgcn_global_load_lds(                                                \
        (const __attribute__((address_space(1))) void*)(gsrc),                       \
        (__attribute__((address_space(3))) void*)(ldst), 16, 0, 0)

// ---------------- pure stream: outb = bf16(x) ----------------
__global__ __launch_bounds__(256) void copy_cvt_kernel(const float* __restrict__ x,
                                                       __hip_bfloat16* __restrict__ outb,
                                                       int n4) {
    int stride = gridDim.x * blockDim.x;
    for (int i = blockIdx.x * blockDim.x + threadIdx.x; i < n4; i += stride) {
        float4 v = reinterpret_cast<const float4*>(x)[i];
        reinterpret_cast<uint2*>(outb)[i] = pk4(v);
    }
}

// ---------------- mean over S from bf16 outb (two-stage, deterministic) ----------------
__global__ __launch_bounds__(256) void mean_stage1(const __hip_bfloat16* __restrict__ xb,
                                                   float* __restrict__ part) {
    int b = blockIdx.x >> 6, sc = blockIdx.x & 63;
    size_t base = ((size_t)b * PS + (size_t)sc * 64) * PD;
    const uint2* x2 = reinterpret_cast<const uint2*>(xb + base);
    int t = threadIdx.x;
    float4 acc = make_float4(0.f, 0.f, 0.f, 0.f);
    for (int r = 0; r < 64; ++r) {
        float4 v = ubf2f4(x2[r * 256 + t]);
        acc.x += v.x; acc.y += v.y; acc.z += v.z; acc.w += v.w;
    }
    reinterpret_cast<float4*>(part + ((size_t)(b * 64 + sc)) * PD)[t] = acc;
}

__global__ __launch_bounds__(256) void mean_stage2(const float* __restrict__ part,
                                                   float* __restrict__ gc) {
    int b = blockIdx.x, t = threadIdx.x;
    float4 s = make_float4(0.f, 0.f, 0.f, 0.f);
    for (int c = 0; c < 64; ++c) {
        float4 v = reinterpret_cast<const float4*>(part + ((size_t)(b * 64 + c)) * PD)[t];
        s.x += v.x; s.y += v.y; s.z += v.z; s.w += v.w;
    }
    s.x *= (1.0f / 4096.0f); s.y *= (1.0f / 4096.0f);
    s.z *= (1.0f / 4096.0f); s.w *= (1.0f / 4096.0f);
    reinterpret_cast<float4*>(gc + (size_t)b * PD)[t] = s;
}

// ---------------- weight transpose+convert: W[K][N] f32 -> Wt[N][K] bf16 ----------------
__global__ __launch_bounds__(256) void transpose_w_kernel(const float* __restrict__ W,
                                                          __hip_bfloat16* __restrict__ Wt,
                                                          int K, int N) {
    __shared__ float t[32][33];
    int k0 = blockIdx.x * 32, n0 = blockIdx.y * 32;
    int tx = threadIdx.x & 31, ty = threadIdx.x >> 5;  // ty 0..7
#pragma unroll
    for (int i = 0; i < 32; i += 8)
        t[ty + i][tx] = W[(size_t)(k0 + ty + i) * N + n0 + tx];
    __syncthreads();
#pragma unroll
    for (int i = 0; i < 32; i += 8)
        Wt[(size_t)(n0 + ty + i) * K + k0 + tx] = __float2bfloat16(t[tx][ty + i]);
}

// ---------------- global context net, parallelized ----------------
__global__ __launch_bounds__(256) void gn1_kernel(const float* __restrict__ gc,
                                                  const float* __restrict__ w1,
                                                  const float* __restrict__ b1,
                                                  float* __restrict__ g1) {
    __shared__ float gcs[1024];
    __shared__ float red[4][64];
    int b = blockIdx.x, j0 = blockIdx.y * 64;
    int t = threadIdx.x, wave = t >> 6, lane = t & 63;
    for (int i = t; i < 1024; i += 256) gcs[i] = gc[(size_t)b * PD + i];
    __syncthreads();
    int j = j0 + lane;
    float a = 0.f;
    int k0 = wave * 256;
    for (int k = k0; k < k0 + 256; ++k) a += gcs[k] * w1[(size_t)k * 512 + j];
    red[wave][lane] = a;
    __syncthreads();
    if (wave == 0) {
        float v = red[0][lane] + red[1][lane] + red[2][lane] + red[3][lane] + b1[j];
        g1[(size_t)b * 512 + j] = geluf(v);
    }
}

__global__ __launch_bounds__(256) void gn2_kernel(const float* __restrict__ g1,
                                                  const float* __restrict__ w2,
                                                  const float* __restrict__ b2,
                                                  float* __restrict__ g2) {
    __shared__ float g1s[512];
    __shared__ float red[4][64];
    int b = blockIdx.x, j0 = blockIdx.y * 64;
    int t = threadIdx.x, wave = t >> 6, lane = t & 63;
    for (int i = t; i < 512; i += 256) g1s[i] = g1[(size_t)b * 512 + i];
    __syncthreads();
    int j = j0 + lane;
    float a = 0.f;
    int k0 = wave * 128;
    for (int k = k0; k < k0 + 128; ++k) a += g1s[k] * w2[(size_t)k * 256 + j];
    red[wave][lane] = a;
    __syncthreads();
    if (wave == 0) {
        float v = red[0][lane] + red[1][lane] + red[2][lane] + red[3][lane] + b2[j];
        g2[(size_t)b * 256 + j] = geluf(v);
    }
}

__global__ __launch_bounds__(256) void gn3_kernel(const float* __restrict__ g2,
                                                  const float* __restrict__ w3,
                                                  const float* __restrict__ b3,
                                                  float* __restrict__ gf) {
    __shared__ float red[256];
    int b = blockIdx.x, t = threadIdx.x;
    red[t] = g2[(size_t)b * 256 + t] * w3[t];
    __syncthreads();
    for (int s = 128; s > 0; s >>= 1) {
        if (t < s) red[t] += red[t + s];
        __syncthreads();
    }
    if (t == 0) gf[b] = sigmf_(red[0] + b3[0]);
}

// ============ 256x128 BK=32 MFMA GEMM — wave tile 128x64 (FLOP/LDS-byte 42.7) ============
// C[m][n] = gelu(sum_k A[m][k]*Wt[n][k] + bias[n]).
// 256 threads = 4 waves (2M x 2N): wave tile 128 rows x 64 cols; acc[8][4].
// LDS: A[256][32] (16KB) + B[128][32] (8KB), dbuf = 96 KB -> 2 blocks/CU.
// Rows are 64B; swizzle byte ^= (((row>>1)&3)<<4): 16-lane ds_read_b128 groups land
// 2 lanes/bank-quad (free, m136). Staging source pre-swizzled (row invariant).
// Per K-tile/wave: 12 ds_read_b128 (read-once), 32 MFMA; one __syncthreads.
template <int EPI>   // 0 = bias+gelu store, 1 = pdot epilogue
__global__ __launch_bounds__(256, 2) void gemm256x128_kernel(
    const __hip_bfloat16* __restrict__ A,
    const __hip_bfloat16* __restrict__ Wt,
    const float* __restrict__ bias,
    const float* __restrict__ w4,
    __hip_bfloat16* __restrict__ C,
    float* __restrict__ pdot,
    int K, int N) {
    __shared__ __align__(16) __hip_bfloat16 Als[2][256 * 32];
    __shared__ __align__(16) __hip_bfloat16 Bls[2][128 * 32];
    __shared__ float spd[EPI ? 256 : 1][2];
    const int tid = threadIdx.x;
    const int wave = tid >> 6, lane = tid & 63;
    const int m0 = blockIdx.x * 256, n0 = blockIdx.y * 128;
    const int wr = wave >> 1, wc = wave & 1;
    const int fr = lane & 15, fq = lane >> 4;

    // ---- staging geometry: A = 1024 chunks (4 rounds), B = 512 chunks (2 rounds) ----
    int sAr[4], sAk[4], sAb[4];
#pragma unroll
    for (int j = 0; j < 4; ++j) {
        int c = j * 256 + wave * 64 + lane;
        int P = c * 16;
        int row = P >> 6;
        int off = (P & 63) ^ (((row >> 1) & 3) << 4);
        sAr[j] = row;
        sAk[j] = off >> 1;
        sAb[j] = (j * 256 + wave * 64) * 16;
    }
    int sBr[2], sBk[2], sBb[2];
#pragma unroll
    for (int j = 0; j < 2; ++j) {
        int c = j * 256 + wave * 64 + lane;
        int P = c * 16;
        int row = P >> 6;
        int off = (P & 63) ^ (((row >> 1) & 3) << 4);
        sBr[j] = row;
        sBk[j] = off >> 1;
        sBb[j] = (j * 256 + wave * 64) * 16;
    }
    // ---- per-lane ds_read byte offsets ----
    int abyte[8], bbyte[4];
#pragma unroll
    for (int fm = 0; fm < 8; ++fm) {
        int row = wr * 128 + fm * 16 + fr;
        abyte[fm] = (row * 64 + fq * 16) ^ (((row >> 1) & 3) << 4);
    }
#pragma unroll
    for (int fn = 0; fn < 4; ++fn) {
        int row = wc * 64 + fn * 16 + fr;
        bbyte[fn] = (row * 64 + fq * 16) ^ (((row >> 1) & 3) << 4);
    }

    f32x4 acc[8][4] = {};
    bf16x8 av[4], bv[4];

#define STAGE(bufn, kt) do {                                                          \
    _Pragma("unroll") for (int j = 0; j < 4; ++j)                                     \
        GLD_LDS16(A + (size_t)(m0 + sAr[j]) * K + (kt) + sAk[j], (char*)Als[bufn] + sAb[j]); \
    _Pragma("unroll") for (int j = 0; j < 2; ++j)                                     \
        GLD_LDS16(Wt + (size_t)(n0 + sBr[j]) * K + (kt) + sBk[j], (char*)Bls[bufn] + sBb[j]); \
} while (0)

    STAGE(0, 0);
    __syncthreads();

    const int nt = K >> 5;
    for (int t = 0; t < nt; ++t) {
        const int buf = t & 1;
        // B frags (4) + A half 0 (4)
#pragma unroll
        for (int ni = 0; ni < 4; ++ni)
            bv[ni] = *(const bf16x8*)((const char*)&Bls[buf][0] + bbyte[ni]);
#pragma unroll
        for (int mi = 0; mi < 4; ++mi)
            av[mi] = *(const bf16x8*)((const char*)&Als[buf][0] + abyte[mi]);
        if (t + 1 < nt) STAGE(buf ^ 1, (t + 1) << 5);
        __builtin_amdgcn_s_setprio(1);
#pragma unroll
        for (int mi = 0; mi < 4; ++mi)
#pragma unroll
            for (int ni = 0; ni < 4; ++ni)
                acc[mi][ni] = __builtin_amdgcn_mfma_f32_16x16x32_bf16(
                    av[mi], bv[ni], acc[mi][ni], 0, 0, 0);
        __builtin_amdgcn_s_setprio(0);
        // A half 1 (reuse av regs; bv stays live)
#pragma unroll
        for (int mi = 0; mi < 4; ++mi)
            av[mi] = *(const bf16x8*)((const char*)&Als[buf][0] + abyte[4 + mi]);
        __builtin_amdgcn_s_setprio(1);
#pragma unroll
        for (int mi = 0; mi < 4; ++mi)
#pragma unroll
            for (int ni = 0; ni < 4; ++ni)
                acc[4 + mi][ni] = __builtin_amdgcn_mfma_f32_16x16x32_bf16(
                    av[mi], bv[ni], acc[4 + mi][ni], 0, 0, 0);
        __builtin_amdgcn_s_setprio(0);
        __syncthreads();
    }

    if (EPI == 0) {
        // bias + gelu + bf16 store
#pragma unroll
        for (int fm = 0; fm < 8; ++fm) {
#pragma unroll
            for (int fn = 0; fn < 4; ++fn) {
                int n = n0 + wc * 64 + fn * 16 + fr;
                float bs = bias[n];
#pragma unroll
                for (int r = 0; r < 4; ++r) {
                    int m = m0 + wr * 128 + fm * 16 + fq * 4 + r;
                    C[(size_t)m * N + n] = __float2bfloat16(gelu_fast(acc[fm][fn][r] + bs));
                }
            }
        }
    } else {
        // pdot: per-row partial dot over this block's 128 columns (deterministic)
        float pd[8][4];
#pragma unroll
        for (int fm = 0; fm < 8; ++fm)
#pragma unroll
            for (int r = 0; r < 4; ++r) {
                float s = 0.f;
#pragma unroll
                for (int fn = 0; fn < 4; ++fn) {
                    int n = n0 + wc * 64 + fn * 16 + fr;
                    s += gelu_fast(acc[fm][fn][r] + bias[n]) * w4[n];
                }
                pd[fm][r] = s;
            }
#pragma unroll
        for (int off = 1; off < 16; off <<= 1)
#pragma unroll
            for (int fm = 0; fm < 8; ++fm)
#pragma unroll
                for (int r = 0; r < 4; ++r)
                    pd[fm][r] += __shfl_xor(pd[fm][r], off);
        if (fr == 0) {
#pragma unroll
            for (int fm = 0; fm < 8; ++fm)
#pragma unroll
                for (int r = 0; r < 4; ++r)
                    spd[wr * 128 + fm * 16 + fq * 4 + r][wc] = pd[fm][r];
        }
        __syncthreads();
        pdot[(size_t)(m0 + tid) * 2 + blockIdx.y] = spd[tid][0] + spd[tid][1];
    }
#undef STAGE
}

// ---------------- tf + coupling + twist update; bf16 state between cycles ----------------
__global__ __launch_bounds__(256) void tf_update_kernel(
    const float* __restrict__ srcf, const __hip_bfloat16* __restrict__ srcb, int use_bf,
    const float* __restrict__ pdot,  // [ROWS][2]
    const float* __restrict__ b4,
    const float* __restrict__ gf, const float* __restrict__ arp,
    float* __restrict__ out, __hip_bfloat16* __restrict__ outb, int wf, int wb) {
    const int wid = threadIdx.x >> 6, lane = threadIdx.x & 63;
    const int r = blockIdx.x * 4 + wid;
    const int b = r >> 12;  // S = 4096 rows per batch

    float2 pv = reinterpret_cast<const float2*>(pdot)[r];
    float tf = sigmf_(pv.x + pv.y + b4[0]);
    float comb = 0.7f * gf[b] + 0.3f * tf;
    float c = BASE_COUPLING + arp[0] * (comb - 0.5f) * 2.0f;

    float4 o_r, o_i, p_r, p_i;
    if (use_bf) {
        const uint2* s2 = reinterpret_cast<const uint2*>(srcb + (size_t)r * PD);
        o_r = ubf2f4(s2[lane]);
        o_i = ubf2f4(s2[64 + lane]);
        p_r = ubf2f4(s2[128 + lane]);
        p_i = ubf2f4(s2[192 + lane]);
    } else {
        const float4* s4 = reinterpret_cast<const float4*>(srcf + (size_t)r * PD);
        o_r = s4[lane];
        o_i = s4[64 + lane];
        p_r = s4[128 + lane];
        p_i = s4[192 + lane];
    }
    float4 n0 = axpy4(o_r, c, p_r);
    float4 n1 = axpy4(o_i, -c, p_i);
    float4 n2 = axpy4(p_r, -c, o_r);
    float4 n3 = axpy4(p_i, c, o_i);
    if (wf) {
        float4* row4 = reinterpret_cast<float4*>(out + (size_t)r * PD);
        row4[lane] = n0;
        row4[64 + lane] = n1;
        row4[128 + lane] = n2;
        row4[192 + lane] = n3;
    }
    if (wb) {
        uint2* rb4 = reinterpret_cast<uint2*>(outb + (size_t)r * PD);
        rb4[lane] = pk4(n0);
        rb4[64 + lane] = pk4(n1);
        rb4[128 + lane] = pk4(n2);
        rb4[192 + lane] = pk4(n3);
    }
}

// ---------------- launch ----------------
extern "C" void kernel_launch(void* const* d_in, const int* in_sizes, int n_in,
                              void* d_out, int out_size, void* d_ws, size_t ws_size,
                              hipStream_t stream) {
    const float* x     = (const float*)d_in[0];
    const float* cn_w1 = (const float*)d_in[1];
    const float* cn_b1 = (const float*)d_in[2];
    const float* cn_w2 = (const float*)d_in[3];
    const float* cn_b2 = (const float*)d_in[4];
    const float* cn_w3 = (const float*)d_in[5];
    const float* cn_b3 = (const float*)d_in[6];
    const float* cn_w4 = (const float*)d_in[7];
    const float* cn_b4 = (const float*)d_in[8];
    const float* gc_w1 = (const float*)d_in[9];
    const float* gc_b1 = (const float*)d_in[10];
    const float* gc_w2 = (const float*)d_in[11];
    const float* gc_b2 = (const float*)d_in[12];
    const float* gc_w3 = (const float*)d_in[13];
    const float* gc_b3 = (const float*)d_in[14];
    const float* ar    = (const float*)d_in[15];

    float* out = (float*)d_out;

    char* ws = (char*)d_ws;
    __hip_bfloat16* h1   = (__hip_bfloat16*)(ws);                      // 32 MB
    __hip_bfloat16* h2   = (__hip_bfloat16*)(ws + ((size_t)32 << 20)); // 16 MB
    __hip_bfloat16* outb = (__hip_bfloat16*)(ws + ((size_t)56 << 20)); // 32 MB
    __hip_bfloat16* wt1  = (__hip_bfloat16*)(ws + ((size_t)88 << 20)); // 2 MB
    __hip_bfloat16* wt2  = (__hip_bfloat16*)(ws + ((size_t)90 << 20)); // 1 MB
    __hip_bfloat16* wt3  = (__hip_bfloat16*)(ws + ((size_t)91 << 20)); // 0.25 MB
    float* pdot          = (float*)(ws + ((size_t)91 << 20) + (1 << 18));  // 128 KB
    float* part          = (float*)(ws + ((size_t)91 << 20) + (3 << 17));  // 1 MB
    float* gc            = part + 4 * 64 * PD;
    float* g1            = gc + 4 * PD;
    float* g2            = g1 + 4 * 512;
    float* gf            = g2 + 4 * 256;

    transpose_w_kernel<<<dim3(32, 32), 256, 0, stream>>>(cn_w1, wt1, 1024, 1024);
    transpose_w_kernel<<<dim3(32, 16), 256, 0, stream>>>(cn_w2, wt2, 1024, 512);
    transpose_w_kernel<<<dim3(16, 8), 256, 0, stream>>>(cn_w3, wt3, 512, 256);

    copy_cvt_kernel<<<2048, 256, 0, stream>>>(x, outb, ROWS * PD / 4);
    mean_stage1<<<256, 256, 0, stream>>>(outb, part);
    mean_stage2<<<PB, 256, 0, stream>>>(part, gc);

    gn1_kernel<<<dim3(PB, 8), 256, 0, stream>>>(gc, gc_w1, gc_b1, g1);
    gn2_kernel<<<dim3(PB, 4), 256, 0, stream>>>(g1, gc_w2, gc_b2, g2);
    gn3_kernel<<<PB, 256, 0, stream>>>(g2, gc_w3, gc_b3, gf);

    for (int cyc = 0; cyc < NUM_CYCLES; ++cyc) {
        gemm256x128_kernel<0><<<dim3(64, 8), 256, 0, stream>>>(
            outb, wt1, cn_b1, nullptr, h1, nullptr, 1024, 1024);
        gemm256x128_kernel<0><<<dim3(64, 4), 256, 0, stream>>>(
            h1, wt2, cn_b2, nullptr, h2, nullptr, 1024, 512);
        gemm256x128_kernel<1><<<dim3(64, 2), 256, 0, stream>>>(
            h2, wt3, cn_b3, cn_w4, nullptr, pdot, 512, 256);
        int last = (cyc + 1 == NUM_CYCLES);
        tf_update_kernel<<<ROWS / 4, 256, 0, stream>>>(
            x, outb, (cyc > 0) ? 1 : 0, pdot, cn_b4, gf, ar,
            out, outb, last ? 1 : 0, last ? 0 : 1);
    }
}

// Round 13
// 322.814 us; speedup vs baseline: 1.1315x; 1.1315x over previous
//
#include <hip/hip_runtime.h>
#include <hip/hip_bf16.h>

// Problem constants (AdaptiveMobiusLayer): B=4, S=4096, DIM=1024
#define PB 4
#define PS 4096
#define PD 1024
#define ROWS (PB * PS)          // 16384
#define NUM_CYCLES 3
#define BASE_COUPLING 0.1f

typedef __attribute__((ext_vector_type(8))) short bf16x8;
typedef __attribute__((ext_vector_type(4))) float f32x4;

// ---------------- helpers ----------------
__device__ __forceinline__ float geluf(float x) {
    return 0.5f * x * (1.0f + erff(x * 0.70710678118654752440f));
}
__device__ __forceinline__ float gelu_fast(float x) {
    float u = (x + 0.044715f * x * x * x) * 2.3022077f;  // 2*0.7978845608*log2(e)
    return x * __builtin_amdgcn_rcpf(1.0f + exp2f(-u));
}
__device__ __forceinline__ float sigmf_(float x) {
    return 1.0f / (1.0f + expf(-x));
}
__device__ __forceinline__ uint2 pk4(float4 v) {
    __hip_bfloat16 h[4] = {__float2bfloat16(v.x), __float2bfloat16(v.y),
                           __float2bfloat16(v.z), __float2bfloat16(v.w)};
    return *reinterpret_cast<uint2*>(h);
}
__device__ __forceinline__ float4 axpy4(float4 a, float s, float4 b) {
    return make_float4(fmaf(s, b.x, a.x), fmaf(s, b.y, a.y),
                       fmaf(s, b.z, a.z), fmaf(s, b.w, a.w));
}
__device__ __forceinline__ float bf2f(unsigned short u) {
    unsigned int w = ((unsigned int)u) << 16;
    return __builtin_bit_cast(float, w);
}
__device__ __forceinline__ float4 ubf2f4(uint2 u) {
    unsigned short h[4];
    *reinterpret_cast<uint2*>(h) = u;
    return make_float4(bf2f(h[0]), bf2f(h[1]), bf2f(h[2]), bf2f(h[3]));
}

#define GLD_LDS16(gsrc, ldst)                                                        \
    __builtin_amdgcn_global_load_lds(                                                \
        (const __attribute__((address_space(1))) void*)(gsrc),                       \
        (__attribute__((address_space(3))) void*)(ldst), 16, 0, 0)

#define ASM_VMCNT4() asm volatile("s_waitcnt vmcnt(4)" ::: "memory")
#define ASM_VMCNT2() asm volatile("s_waitcnt vmcnt(2)" ::: "memory")
#define ASM_VMCNT0() asm volatile("s_waitcnt vmcnt(0)" ::: "memory")
#define ASM_LGKM0()  asm volatile("s_waitcnt lgkmcnt(0)" ::: "memory")
#define SCHED_FENCE() __builtin_amdgcn_sched_barrier(0)
#define BAR() __builtin_amdgcn_s_barrier()

// ---------------- pure stream: outb = bf16(x) ----------------
__global__ __launch_bounds__(256) void copy_cvt_kernel(const float* __restrict__ x,
                                                       __hip_bfloat16* __restrict__ outb,
                                                       int n4) {
    int stride = gridDim.x * blockDim.x;
    for (int i = blockIdx.x * blockDim.x + threadIdx.x; i < n4; i += stride) {
        float4 v = reinterpret_cast<const float4*>(x)[i];
        reinterpret_cast<uint2*>(outb)[i] = pk4(v);
    }
}

// ---------------- mean over S from bf16 outb (two-stage, deterministic) ----------------
__global__ __launch_bounds__(256) void mean_stage1(const __hip_bfloat16* __restrict__ xb,
                                                   float* __restrict__ part) {
    int b = blockIdx.x >> 6, sc = blockIdx.x & 63;
    size_t base = ((size_t)b * PS + (size_t)sc * 64) * PD;
    const uint2* x2 = reinterpret_cast<const uint2*>(xb + base);
    int t = threadIdx.x;
    float4 acc = make_float4(0.f, 0.f, 0.f, 0.f);
    for (int r = 0; r < 64; ++r) {
        float4 v = ubf2f4(x2[r * 256 + t]);
        acc.x += v.x; acc.y += v.y; acc.z += v.z; acc.w += v.w;
    }
    reinterpret_cast<float4*>(part + ((size_t)(b * 64 + sc)) * PD)[t] = acc;
}

__global__ __launch_bounds__(256) void mean_stage2(const float* __restrict__ part,
                                                   float* __restrict__ gc) {
    int b = blockIdx.x, t = threadIdx.x;
    float4 s = make_float4(0.f, 0.f, 0.f, 0.f);
    for (int c = 0; c < 64; ++c) {
        float4 v = reinterpret_cast<const float4*>(part + ((size_t)(b * 64 + c)) * PD)[t];
        s.x += v.x; s.y += v.y; s.z += v.z; s.w += v.w;
    }
    s.x *= (1.0f / 4096.0f); s.y *= (1.0f / 4096.0f);
    s.z *= (1.0f / 4096.0f); s.w *= (1.0f / 4096.0f);
    reinterpret_cast<float4*>(gc + (size_t)b * PD)[t] = s;
}

// ---------------- weight transpose+convert: W[K][N] f32 -> Wt[N][K] bf16 ----------------
__global__ __launch_bounds__(256) void transpose_w_kernel(const float* __restrict__ W,
                                                          __hip_bfloat16* __restrict__ Wt,
                                                          int K, int N) {
    __shared__ float t[32][33];
    int k0 = blockIdx.x * 32, n0 = blockIdx.y * 32;
    int tx = threadIdx.x & 31, ty = threadIdx.x >> 5;  // ty 0..7
#pragma unroll
    for (int i = 0; i < 32; i += 8)
        t[ty + i][tx] = W[(size_t)(k0 + ty + i) * N + n0 + tx];
    __syncthreads();
#pragma unroll
    for (int i = 0; i < 32; i += 8)
        Wt[(size_t)(n0 + ty + i) * K + k0 + tx] = __float2bfloat16(t[tx][ty + i]);
}

// ---------------- global context net, parallelized ----------------
__global__ __launch_bounds__(256) void gn1_kernel(const float* __restrict__ gc,
                                                  const float* __restrict__ w1,
                                                  const float* __restrict__ b1,
                                                  float* __restrict__ g1) {
    __shared__ float gcs[1024];
    __shared__ float red[4][64];
    int b = blockIdx.x, j0 = blockIdx.y * 64;
    int t = threadIdx.x, wave = t >> 6, lane = t & 63;
    for (int i = t; i < 1024; i += 256) gcs[i] = gc[(size_t)b * PD + i];
    __syncthreads();
    int j = j0 + lane;
    float a = 0.f;
    int k0 = wave * 256;
    for (int k = k0; k < k0 + 256; ++k) a += gcs[k] * w1[(size_t)k * 512 + j];
    red[wave][lane] = a;
    __syncthreads();
    if (wave == 0) {
        float v = red[0][lane] + red[1][lane] + red[2][lane] + red[3][lane] + b1[j];
        g1[(size_t)b * 512 + j] = geluf(v);
    }
}

__global__ __launch_bounds__(256) void gn2_kernel(const float* __restrict__ g1,
                                                  const float* __restrict__ w2,
                                                  const float* __restrict__ b2,
                                                  float* __restrict__ g2) {
    __shared__ float g1s[512];
    __shared__ float red[4][64];
    int b = blockIdx.x, j0 = blockIdx.y * 64;
    int t = threadIdx.x, wave = t >> 6, lane = t & 63;
    for (int i = t; i < 512; i += 256) g1s[i] = g1[(size_t)b * 512 + i];
    __syncthreads();
    int j = j0 + lane;
    float a = 0.f;
    int k0 = wave * 128;
    for (int k = k0; k < k0 + 128; ++k) a += g1s[k] * w2[(size_t)k * 256 + j];
    red[wave][lane] = a;
    __syncthreads();
    if (wave == 0) {
        float v = red[0][lane] + red[1][lane] + red[2][lane] + red[3][lane] + b2[j];
        g2[(size_t)b * 256 + j] = geluf(v);
    }
}

__global__ __launch_bounds__(256) void gn3_kernel(const float* __restrict__ g2,
                                                  const float* __restrict__ w3,
                                                  const float* __restrict__ b3,
                                                  float* __restrict__ gf) {
    __shared__ float red[256];
    int b = blockIdx.x, t = threadIdx.x;
    red[t] = g2[(size_t)b * 256 + t] * w3[t];
    __syncthreads();
    for (int s = 128; s > 0; s >>= 1) {
        if (t < s) red[t] += red[t + s];
        __syncthreads();
    }
    if (t == 0) gf[b] = sigmf_(red[0] + b3[0]);
}

// ============ 256x256 8-PHASE MFMA GEMM (faithful T3+T4 port), layer 1 ============
// BM=BN=256, BK=64, 512 thr = 8 waves (2M x 4N), wave tile 128x64, acc[8][4].
// LDS: A[2][256][64] + B[2][256][64] bf16 = 128 KB (1 block/CU).
// Swizzle (both sides, HW-verified): phys_byte = logical ^ ((row&7)<<4), kk slice ^64B.
// Per K-tile, 4 phases; staging units (2 GLD/thread each) issued one-per-phase in
// order A0,B0,B1,A1 (A0={rows 0-63,128-191}, B0={cols 0-31,64-95,128-159,192-223},
// B1/A1 complements). Counted vmcnt(4) at ph1/ph2/ph4 ends -> each unit >=3 phases
// of latency cover, never drained to 0 mid-loop. Per phase: read-once register
// subtile + lgkmcnt(0) + setprio-wrapped 16 MFMA + raw s_barrier.
__global__ __launch_bounds__(512, 1) void gemm8p_kernel(
    const __hip_bfloat16* __restrict__ A,
    const __hip_bfloat16* __restrict__ Wt,
    const float* __restrict__ bias,
    __hip_bfloat16* __restrict__ C,
    int K, int N) {
    __shared__ __align__(16) __hip_bfloat16 Als[2][256 * 64];
    __shared__ __align__(16) __hip_bfloat16 Bls[2][256 * 64];
    const int tid = threadIdx.x;
    const int wave = tid >> 6, lane = tid & 63;
    const int nbn = N >> 8;
    const int nwg = gridDim.x;
    const int bid = blockIdx.x;
    const int swz = (bid & 7) * (nwg >> 3) + (bid >> 3);   // nwg % 8 == 0
    const int m0 = (swz / nbn) * 256, n0 = (swz % nbn) * 256;
    const int wr = wave >> 2, wc = wave & 3;
    const int fr = lane & 15, fq = lane >> 4;

    // ---- staging: unit u, round r -> source elem offset + wave-uniform LDS base ----
    // A0 (u=0): row = r*128 + ((wave*64+lane)>>3);        lbase = r*16384 + wave*1024
    // B0 (u=1): g=r*2+(wave>>2), cc=(wave&3)*64+lane; row = g*64 + (cc>>3);
    //           lbase = g*8192 + (wave&3)*1024
    // B1 (u=2): row = g*64+32+(cc>>3);  lbase = g*8192 + 4096 + (wave&3)*1024
    // A1 (u=3): row = 64 + r*128 + ((wave*64+lane)>>3);  lbase = 8192 + r*16384 + wave*1024
    int srcoff[4][2], cb[4][2];
#pragma unroll
    for (int r = 0; r < 2; ++r) {
        int binrow = (lane & 7) * 16;          // byte-in-row (same for all units)
        // A units
        int rowA0 = r * 128 + ((wave * 64 + lane) >> 3);
        int rowA1 = 64 + rowA0;
        // B units
        int g = r * 2 + (wave >> 2);
        int cc = (wave & 3) * 64 + lane;
        int rowB0 = g * 64 + (cc >> 3);
        int rowB1 = rowB0 + 32;
        int kA0 = (binrow ^ ((rowA0 & 7) << 4)) >> 1;
        int kA1 = (binrow ^ ((rowA1 & 7) << 4)) >> 1;
        int kB0 = (binrow ^ ((rowB0 & 7) << 4)) >> 1;
        int kB1 = (binrow ^ ((rowB1 & 7) << 4)) >> 1;
        srcoff[0][r] = (m0 + rowA0) * K + kA0;
        srcoff[1][r] = (n0 + rowB0) * K + kB0;
        srcoff[2][r] = (n0 + rowB1) * K + kB1;
        srcoff[3][r] = (m0 + rowA1) * K + kA1;
        cb[0][r] = r * 16384 + wave * 1024;
        cb[1][r] = g * 8192 + (wave & 3) * 1024;
        cb[2][r] = g * 8192 + 4096 + (wave & 3) * 1024;
        cb[3][r] = 8192 + r * 16384 + wave * 1024;
    }
    // ---- ds_read byte offsets (kk slice toggles byte 64) ----
    int abyte[8], bbyte[4];
#pragma unroll
    for (int fm = 0; fm < 8; ++fm) {
        int row = wr * 128 + fm * 16 + fr;
        abyte[fm] = (row * 128 + fq * 16) ^ ((row & 7) << 4);
    }
#pragma unroll
    for (int fn = 0; fn < 4; ++fn) {
        int row = wc * 64 + fn * 16 + fr;
        bbyte[fn] = (row * 128 + fq * 16) ^ ((row & 7) << 4);
    }

    f32x4 acc[8][4] = {};
    bf16x8 av[4][2], bv01[2][2], bv23[2][2];

#define STG(u, bufn, kt) do {                                                        \
    const __hip_bfloat16* sb_ = ((u) == 0 || (u) == 3) ? A : Wt;                     \
    __hip_bfloat16* lb_ = ((u) == 0 || (u) == 3) ? &Als[bufn][0] : &Bls[bufn][0];    \
    GLD_LDS16(sb_ + srcoff[u][0] + (kt), (char*)lb_ + cb[u][0]);                     \
    GLD_LDS16(sb_ + srcoff[u][1] + (kt), (char*)lb_ + cb[u][1]);                     \
} while (0)

#define RD_A(BUF, H)                                                                 \
    _Pragma("unroll") for (int mi = 0; mi < 4; ++mi)                                 \
      _Pragma("unroll") for (int kk = 0; kk < 2; ++kk)                               \
        av[mi][kk] = *(const bf16x8*)((const char*)&Als[BUF][0] + (abyte[(H)*4 + mi] ^ (kk << 6)));
#define RD_B(BUF, H, DST)                                                            \
    _Pragma("unroll") for (int ni = 0; ni < 2; ++ni)                                 \
      _Pragma("unroll") for (int kk = 0; kk < 2; ++kk)                               \
        DST[ni][kk] = *(const bf16x8*)((const char*)&Bls[BUF][0] + (bbyte[(H)*2 + ni] ^ (kk << 6)));
#define MFMAQ(MH, NH, BV)                                                            \
    __builtin_amdgcn_s_setprio(1);                                                   \
    _Pragma("unroll") for (int kk = 0; kk < 2; ++kk)                                 \
      _Pragma("unroll") for (int mi = 0; mi < 4; ++mi)                               \
        _Pragma("unroll") for (int ni = 0; ni < 2; ++ni)                             \
          acc[(MH)*4 + mi][(NH)*2 + ni] = __builtin_amdgcn_mfma_f32_16x16x32_bf16(   \
              av[mi][kk], BV[ni][kk], acc[(MH)*4 + mi][(NH)*2 + ni], 0, 0, 0);       \
    __builtin_amdgcn_s_setprio(0);

    // ---- prologue: stage tile 0 fully ----
    STG(0, 0, 0); STG(1, 0, 0); STG(2, 0, 0); STG(3, 0, 0);
    ASM_VMCNT0();
    BAR();

    const int nt = K >> 6;
    for (int t = 0; t < nt; ++t) {
        const int buf = t & 1;
        const int nbuf = buf ^ 1;
        const int ktn = (t + 1) << 6;
        const bool pf = (t + 1 < nt);
        // ph1: read A-sub0 (8) + B-sub0 (4); stage A0'; MFMA (0,0); vmcnt; bar
        RD_A(buf, 0);
        RD_B(buf, 0, bv01);
        if (pf) STG(0, nbuf, ktn);
        ASM_LGKM0(); SCHED_FENCE();
        MFMAQ(0, 0, bv01);
        if (pf) ASM_VMCNT4(); else ASM_VMCNT2();
        BAR();
        // ph2: read B-sub1 (4); stage B0'; MFMA (0,1); vmcnt; bar
        RD_B(buf, 1, bv23);
        if (pf) STG(1, nbuf, ktn);
        ASM_LGKM0(); SCHED_FENCE();
        MFMAQ(0, 1, bv23);
        if (pf) ASM_VMCNT4(); else ASM_VMCNT0();
        BAR();
        // ph3: read A-sub1 (8); stage B1'; MFMA (1,1); bar
        RD_A(buf, 1);
        if (pf) STG(2, nbuf, ktn);
        ASM_LGKM0(); SCHED_FENCE();
        MFMAQ(1, 1, bv23);
        BAR();
        // ph4: no reads; stage A1'; MFMA (1,0); vmcnt; bar
        if (pf) STG(3, nbuf, ktn);
        MFMAQ(1, 0, bv01);
        if (pf) ASM_VMCNT4();
        BAR();
    }

    // ---- epilogue: bias + fast gelu + bf16 store ----
#pragma unroll
    for (int fm = 0; fm < 8; ++fm) {
#pragma unroll
        for (int fn = 0; fn < 4; ++fn) {
            int n = n0 + wc * 64 + fn * 16 + fr;
            float bs = bias[n];
#pragma unroll
            for (int r = 0; r < 4; ++r) {
                int m = m0 + wr * 128 + fm * 16 + fq * 4 + r;
                C[(size_t)m * N + n] = __float2bfloat16(gelu_fast(acc[fm][fn][r] + bs));
            }
        }
    }
#undef STG
#undef RD_A
#undef RD_B
#undef MFMAQ
}

// ============ 128x128 BK=64 MFMA GEMM — read-once, 64KB LDS -> 2 blocks/CU (R11) ============
__global__ __launch_bounds__(256, 2) void gemm128b64_kernel(
    const __hip_bfloat16* __restrict__ A,
    const __hip_bfloat16* __restrict__ Wt,
    const float* __restrict__ bias,
    __hip_bfloat16* __restrict__ C,
    int K, int N) {
    __shared__ __align__(16) __hip_bfloat16 Als[2][128 * 64];
    __shared__ __align__(16) __hip_bfloat16 Bls[2][128 * 64];
    const int tid = threadIdx.x;
    const int wave = tid >> 6, lane = tid & 63;
    const int m0 = blockIdx.x * 128, n0 = blockIdx.y * 128;
    const int wr = wave >> 1, wc = wave & 1;
    const int fr = lane & 15, fq = lane >> 4;

    int sr[4], sk[4], sbb[4];
#pragma unroll
    for (int j = 0; j < 4; ++j) {
        int c = wave * 64 + j * 256 + lane;
        int P = c * 16;
        int L = P ^ (((P >> 7) & 7) << 4);
        sr[j] = L >> 7;
        sk[j] = (L & 127) >> 1;
        sbb[j] = (wave * 64 + j * 256) * 16;
    }
    int abyte[4], bbyte[4];
#pragma unroll
    for (int f = 0; f < 4; ++f) {
        int rowA = wr * 64 + f * 16 + fr;
        abyte[f] = (rowA * 128 + fq * 16) ^ ((rowA & 7) << 4);
        int rowB = wc * 64 + f * 16 + fr;
        bbyte[f] = (rowB * 128 + fq * 16) ^ ((rowB & 7) << 4);
    }

    f32x4 acc[4][4] = {};
    bf16x8 av[4][2], bv[4][2];

#define STAGE(bufn, kt) do {                                                         \
    _Pragma("unroll") for (int j = 0; j < 4; ++j) {                                  \
        GLD_LDS16(A + (size_t)(m0 + sr[j]) * K + (kt) + sk[j], (char*)Als[bufn] + sbb[j]); \
        GLD_LDS16(Wt + (size_t)(n0 + sr[j]) * K + (kt) + sk[j], (char*)Bls[bufn] + sbb[j]); \
    }                                                                                \
} while (0)

    STAGE(0, 0);
    __syncthreads();

    const int nt = K >> 6;
    for (int t = 0; t < nt; ++t) {
        const int buf = t & 1;
#pragma unroll
        for (int ni = 0; ni < 4; ++ni)
#pragma unroll
            for (int kk = 0; kk < 2; ++kk)
                bv[ni][kk] = *(const bf16x8*)((const char*)&Bls[buf][0] + (bbyte[ni] ^ (kk << 6)));
#pragma unroll
        for (int mi = 0; mi < 4; ++mi)
#pragma unroll
            for (int kk = 0; kk < 2; ++kk)
                av[mi][kk] = *(const bf16x8*)((const char*)&Als[buf][0] + (abyte[mi] ^ (kk << 6)));
        if (t + 1 < nt) STAGE(buf ^ 1, (t + 1) << 6);
        __builtin_amdgcn_s_setprio(1);
#pragma unroll
        for (int kk = 0; kk < 2; ++kk)
#pragma unroll
            for (int mi = 0; mi < 4; ++mi)
#pragma unroll
                for (int ni = 0; ni < 4; ++ni)
                    acc[mi][ni] = __builtin_amdgcn_mfma_f32_16x16x32_bf16(
                        av[mi][kk], bv[ni][kk], acc[mi][ni], 0, 0, 0);
        __builtin_amdgcn_s_setprio(0);
        __syncthreads();
    }

#pragma unroll
    for (int mi = 0; mi < 4; ++mi) {
#pragma unroll
        for (int ni = 0; ni < 4; ++ni) {
            int n = n0 + wc * 64 + ni * 16 + fr;
            float bs = bias[n];
#pragma unroll
            for (int r = 0; r < 4; ++r) {
                int m = m0 + wr * 64 + mi * 16 + fq * 4 + r;
                C[(size_t)m * N + n] = __float2bfloat16(gelu_fast(acc[mi][ni][r] + bs));
            }
        }
    }
#undef STAGE
}

// ============ same core, layer-3: fused tf partial-dot epilogue (R11) ============
__global__ __launch_bounds__(256, 2) void gemm128b64_pdot_kernel(
    const __hip_bfloat16* __restrict__ A,
    const __hip_bfloat16* __restrict__ Wt,
    const float* __restrict__ bias,
    const float* __restrict__ w4,
    float* __restrict__ pdot,   // [M][2]
    int K, int N) {
    __shared__ __align__(16) __hip_bfloat16 Als[2][128 * 64];
    __shared__ __align__(16) __hip_bfloat16 Bls[2][128 * 64];
    __shared__ float spd[128][2];
    const int tid = threadIdx.x;
    const int wave = tid >> 6, lane = tid & 63;
    const int m0 = blockIdx.x * 128, n0 = blockIdx.y * 128;
    const int nb = blockIdx.y;
    const int wr = wave >> 1, wc = wave & 1;
    const int fr = lane & 15, fq = lane >> 4;

    int sr[4], sk[4], sbb[4];
#pragma unroll
    for (int j = 0; j < 4; ++j) {
        int c = wave * 64 + j * 256 + lane;
        int P = c * 16;
        int L = P ^ (((P >> 7) & 7) << 4);
        sr[j] = L >> 7;
        sk[j] = (L & 127) >> 1;
        sbb[j] = (wave * 64 + j * 256) * 16;
    }
    int abyte[4], bbyte[4];
#pragma unroll
    for (int f = 0; f < 4; ++f) {
        int rowA = wr * 64 + f * 16 + fr;
        abyte[f] = (rowA * 128 + fq * 16) ^ ((rowA & 7) << 4);
        int rowB = wc * 64 + f * 16 + fr;
        bbyte[f] = (rowB * 128 + fq * 16) ^ ((rowB & 7) << 4);
    }

    f32x4 acc[4][4] = {};
    bf16x8 av[4][2], bv[4][2];

#define STAGE(bufn, kt) do {                                                         \
    _Pragma("unroll") for (int j = 0; j < 4; ++j) {                                  \
        GLD_LDS16(A + (size_t)(m0 + sr[j]) * K + (kt) + sk[j], (char*)Als[bufn] + sbb[j]); \
        GLD_LDS16(Wt + (size_t)(n0 + sr[j]) * K + (kt) + sk[j], (char*)Bls[bufn] + sbb[j]); \
    }                                                                                \
} while (0)

    STAGE(0, 0);
    __syncthreads();

    const int nt = K >> 6;
    for (int t = 0; t < nt; ++t) {
        const int buf = t & 1;
#pragma unroll
        for (int ni = 0; ni < 4; ++ni)
#pragma unroll
            for (int kk = 0; kk < 2; ++kk)
                bv[ni][kk] = *(const bf16x8*)((const char*)&Bls[buf][0] + (bbyte[ni] ^ (kk << 6)));
#pragma unroll
        for (int mi = 0; mi < 4; ++mi)
#pragma unroll
            for (int kk = 0; kk < 2; ++kk)
                av[mi][kk] = *(const bf16x8*)((const char*)&Als[buf][0] + (abyte[mi] ^ (kk << 6)));
        if (t + 1 < nt) STAGE(buf ^ 1, (t + 1) << 6);
        __builtin_amdgcn_s_setprio(1);
#pragma unroll
        for (int kk = 0; kk < 2; ++kk)
#pragma unroll
            for (int mi = 0; mi < 4; ++mi)
#pragma unroll
                for (int ni = 0; ni < 4; ++ni)
                    acc[mi][ni] = __builtin_amdgcn_mfma_f32_16x16x32_bf16(
                        av[mi][kk], bv[ni][kk], acc[mi][ni], 0, 0, 0);
        __builtin_amdgcn_s_setprio(0);
        __syncthreads();
    }

    float pd[4][4];
#pragma unroll
    for (int mi = 0; mi < 4; ++mi)
#pragma unroll
        for (int r = 0; r < 4; ++r) {
            float s = 0.f;
#pragma unroll
            for (int ni = 0; ni < 4; ++ni) {
                int n = n0 + wc * 64 + ni * 16 + fr;
                s += gelu_fast(acc[mi][ni][r] + bias[n]) * w4[n];
            }
            pd[mi][r] = s;
        }
#pragma unroll
    for (int off = 1; off < 16; off <<= 1)
#pragma unroll
        for (int mi = 0; mi < 4; ++mi)
#pragma unroll
            for (int r = 0; r < 4; ++r)
                pd[mi][r] += __shfl_xor(pd[mi][r], off);
    if (fr == 0) {
#pragma unroll
        for (int mi = 0; mi < 4; ++mi)
#pragma unroll
            for (int r = 0; r < 4; ++r)
                spd[wr * 64 + mi * 16 + fq * 4 + r][wc] = pd[mi][r];
    }
    __syncthreads();
    if (tid < 128) pdot[(size_t)(m0 + tid) * 2 + nb] = spd[tid][0] + spd[tid][1];
#undef STAGE
}

// ---------------- tf + coupling + twist update; bf16 state between cycles ----------------
__global__ __launch_bounds__(256) void tf_update_kernel(
    const float* __restrict__ srcf, const __hip_bfloat16* __restrict__ srcb, int use_bf,
    const float* __restrict__ pdot,  // [ROWS][2]
    const float* __restrict__ b4,
    const float* __restrict__ gf, const float* __restrict__ arp,
    float* __restrict__ out, __hip_bfloat16* __restrict__ outb, int wf, int wb) {
    const int wid = threadIdx.x >> 6, lane = threadIdx.x & 63;
    const int r = blockIdx.x * 4 + wid;
    const int b = r >> 12;  // S = 4096 rows per batch

    float2 pv = reinterpret_cast<const float2*>(pdot)[r];
    float tf = sigmf_(pv.x + pv.y + b4[0]);
    float comb = 0.7f * gf[b] + 0.3f * tf;
    float c = BASE_COUPLING + arp[0] * (comb - 0.5f) * 2.0f;

    float4 o_r, o_i, p_r, p_i;
    if (use_bf) {
        const uint2* s2 = reinterpret_cast<const uint2*>(srcb + (size_t)r * PD);
        o_r = ubf2f4(s2[lane]);
        o_i = ubf2f4(s2[64 + lane]);
        p_r = ubf2f4(s2[128 + lane]);
        p_i = ubf2f4(s2[192 + lane]);
    } else {
        const float4* s4 = reinterpret_cast<const float4*>(srcf + (size_t)r * PD);
        o_r = s4[lane];
        o_i = s4[64 + lane];
        p_r = s4[128 + lane];
        p_i = s4[192 + lane];
    }
    float4 n0 = axpy4(o_r, c, p_r);
    float4 n1 = axpy4(o_i, -c, p_i);
    float4 n2 = axpy4(p_r, -c, o_r);
    float4 n3 = axpy4(p_i, c, o_i);
    if (wf) {
        float4* row4 = reinterpret_cast<float4*>(out + (size_t)r * PD);
        row4[lane] = n0;
        row4[64 + lane] = n1;
        row4[128 + lane] = n2;
        row4[192 + lane] = n3;
    }
    if (wb) {
        uint2* rb4 = reinterpret_cast<uint2*>(outb + (size_t)r * PD);
        rb4[lane] = pk4(n0);
        rb4[64 + lane] = pk4(n1);
        rb4[128 + lane] = pk4(n2);
        rb4[192 + lane] = pk4(n3);
    }
}

// ---------------- launch ----------------
extern "C" void kernel_launch(void* const* d_in, const int* in_sizes, int n_in,
                              void* d_out, int out_size, void* d_ws, size_t ws_size,
                              hipStream_t stream) {
    const float* x     = (const float*)d_in[0];
    const float* cn_w1 = (const float*)d_in[1];
    const float* cn_b1 = (const float*)d_in[2];
    const float* cn_w2 = (const float*)d_in[3];
    const float* cn_b2 = (const float*)d_in[4];
    const float* cn_w3 = (const float*)d_in[5];
    const float* cn_b3 = (const float*)d_in[6];
    const float* cn_w4 = (const float*)d_in[7];
    const float* cn_b4 = (const float*)d_in[8];
    const float* gc_w1 = (const float*)d_in[9];
    const float* gc_b1 = (const float*)d_in[10];
    const float* gc_w2 = (const float*)d_in[11];
    const float* gc_b2 = (const float*)d_in[12];
    const float* gc_w3 = (const float*)d_in[13];
    const float* gc_b3 = (const float*)d_in[14];
    const float* ar    = (const float*)d_in[15];

    float* out = (float*)d_out;

    char* ws = (char*)d_ws;
    __hip_bfloat16* h1   = (__hip_bfloat16*)(ws);                      // 32 MB
    __hip_bfloat16* h2   = (__hip_bfloat16*)(ws + ((size_t)32 << 20)); // 16 MB
    __hip_bfloat16* outb = (__hip_bfloat16*)(ws + ((size_t)56 << 20)); // 32 MB
    __hip_bfloat16* wt1  = (__hip_bfloat16*)(ws + ((size_t)88 << 20)); // 2 MB
    __hip_bfloat16* wt2  = (__hip_bfloat16*)(ws + ((size_t)90 << 20)); // 1 MB
    __hip_bfloat16* wt3  = (__hip_bfloat16*)(ws + ((size_t)91 << 20)); // 0.25 MB
    float* pdot          = (float*)(ws + ((size_t)91 << 20) + (1 << 18));  // 128 KB
    float* part          = (float*)(ws + ((size_t)91 << 20) + (3 << 17));  // 1 MB
    float* gc            = part + 4 * 64 * PD;
    float* g1            = gc + 4 * PD;
    float* g2            = g1 + 4 * 512;
    float* gf            = g2 + 4 * 256;

    transpose_w_kernel<<<dim3(32, 32), 256, 0, stream>>>(cn_w1, wt1, 1024, 1024);
    transpose_w_kernel<<<dim3(32, 16), 256, 0, stream>>>(cn_w2, wt2, 1024, 512);
    transpose_w_kernel<<<dim3(16, 8), 256, 0, stream>>>(cn_w3, wt3, 512, 256);

    copy_cvt_kernel<<<2048, 256, 0, stream>>>(x, outb, ROWS * PD / 4);
    mean_stage1<<<256, 256, 0, stream>>>(outb, part);
    mean_stage2<<<PB, 256, 0, stream>>>(part, gc);

    gn1_kernel<<<dim3(PB, 8), 256, 0, stream>>>(gc, gc_w1, gc_b1, g1);
    gn2_kernel<<<dim3(PB, 4), 256, 0, stream>>>(g1, gc_w2, gc_b2, g2);
    gn3_kernel<<<PB, 256, 0, stream>>>(g2, gc_w3, gc_b3, gf);

    for (int cyc = 0; cyc < NUM_CYCLES; ++cyc) {
        gemm8p_kernel<<<64 * 4, 512, 0, stream>>>(outb, wt1, cn_b1, h1, 1024, 1024);
        gemm128b64_kernel<<<dim3(128, 4), 256, 0, stream>>>(h1, wt2, cn_b2, h2, 1024, 512);
        gemm128b64_pdot_kernel<<<dim3(128, 2), 256, 0, stream>>>(h2, wt3, cn_b3, cn_w4, pdot, 512, 256);
        int last = (cyc + 1 == NUM_CYCLES);
        tf_update_kernel<<<ROWS / 4, 256, 0, stream>>>(
            x, outb, (cyc > 0) ? 1 : 0, pdot, cn_b4, gf, ar,
            out, outb, last ? 1 : 0, last ? 0 : 1);
    }
}